// Round 7
// baseline (253.694 us; speedup 1.0000x reference)
//
#include <hip/hip_runtime.h>
#include <hip/hip_bf16.h>
#include <stdint.h>

typedef __hip_bfloat16 bf16;
typedef __attribute__((ext_vector_type(4))) short short4v;
typedef __attribute__((ext_vector_type(8))) short short8v;
typedef __attribute__((ext_vector_type(4))) float f32x4;

#define CAT8(lo,hi) __builtin_shufflevector(lo, hi, 0,1,2,3,4,5,6,7)
#define MFMA16(a,b,c) __builtin_amdgcn_mfma_f32_16x16x32_bf16(a,b,c,0,0,0)

__device__ __forceinline__ void gload16(const void* g, void* l) {
  __builtin_amdgcn_global_load_lds((const __attribute__((address_space(1))) unsigned int*)g,
                                   (__attribute__((address_space(3))) unsigned int*)l, 16, 0, 0);
}

__device__ __forceinline__ short f2bs(float f) {
  return __builtin_bit_cast(short, __float2bfloat16(f));
}

// byte-offset swizzle within a 128-B LDS row (8 x 16-B chunks): chunk ^= row&7
#define SWZ(b,row) (((b)&15) | ((((((b)>>4)) ^ ((row)&7)) & 7)<<4))

// ---------------- convert x (f32 -> bf16), 4 elems/thread ----------------
__global__ __launch_bounds__(256) void k_cvt_x(const float* __restrict__ in, bf16* __restrict__ out) {
  int i = blockIdx.x*256 + threadIdx.x;
  float4 v = ((const float4*)in)[i];
  bf16* o = out + (size_t)i*4;
  o[0] = __float2bfloat16(v.x); o[1] = __float2bfloat16(v.y);
  o[2] = __float2bfloat16(v.z); o[3] = __float2bfloat16(v.w);
}

// ---------------- transpose-convert: W[K][N] f32 -> Wt[N][K] bf16 ----------------
__global__ __launch_bounds__(256) void k_transpose_cvt(const float* __restrict__ W, bf16* __restrict__ Wt,
                                                       int K, int N) {
  __shared__ float ts[64][65];
  int k0 = blockIdx.y*64, n0 = blockIdx.x*64;
  int t = threadIdx.x;
  #pragma unroll
  for (int ii = 0; ii < 16; ++ii) {
    int idx = ii*256 + t; int r = idx>>6, c = idx&63;
    ts[r][c] = W[(size_t)(k0+r)*N + n0 + c];
  }
  __syncthreads();
  #pragma unroll
  for (int ii = 0; ii < 16; ++ii) {
    int idx = ii*256 + t; int r = idx>>6, c = idx&63;   // r: n-row, c: k-col
    Wt[(size_t)(n0+r)*K + k0 + c] = __float2bfloat16(ts[c][r]);
  }
}

// ---------------- 256x256 split-K GEMM, BK=64, 8 waves, dbuf + counted vmcnt ----------------
// Sync skeleton identical to R6 (proven): STAGE-before-wait, vmcnt(8) (never 0 in
// main loop), raw s_barrier pairs, sched_barrier pins. Tile scaled 4x: 64 MFMA per
// barrier pair, 128 FLOP/staged-byte. LDS 128 KB (1 block/CU). Chunk-XOR swizzle
// (row&7) applied on BOTH sides (pre-swizzled global source + swizzled ds_read).
// XCD-chunked block swizzle (nwg % 8 == 0 for all our grids).
__global__ __launch_bounds__(512, 2) void k_gemm256(const bf16* __restrict__ A, const bf16* __restrict__ Bt,
                                                    float* __restrict__ C, int M, int N, int K,
                                                    int KC, int ldc) {
  __shared__ __align__(1024) bf16 lds[2][2][256*64];   // [dbuf][A=0/B=1][row][k]
  const int t = threadIdx.x;
  const int lane = t & 63, w = t >> 6;
  const int wr = w >> 2, wc = w & 3;                   // 2 (M) x 4 (N) waves
  const int l15 = lane & 15;
  const int kb  = (lane >> 4) << 2;                    // k-quad base of this lane group

  // --- XCD-chunked block-id swizzle (bijective; nwg % 8 == 0) ---
  const int nbx = gridDim.x, nby = gridDim.y;
  const int nwg = nbx*nby*gridDim.z;
  int bid = (blockIdx.z*nby + blockIdx.y)*nbx + blockIdx.x;
  int newid = (bid & 7)*(nwg >> 3) + (bid >> 3);
  int z   = newid / (nbx*nby);
  int rem = newid - z*(nbx*nby);
  const int m0 = (rem / nbx) * 256;
  const int n0 = (rem % nbx) * 256;
  const int kbeg = z * KC;

  f32x4 acc[8][4];
  #pragma unroll
  for (int i = 0; i < 8; ++i)
    #pragma unroll
    for (int j = 0; j < 4; ++j) acc[i][j] = 0.f;

  const char* Ab = (const char*)A;
  const char* Bb = (const char*)Bt;
  const int off = t*16;                                // linear LDS byte offset, batch 0

  // stage one K-tile (256 rows x 64 k, A and B): 4 batches x 8 KB, 8 gloads/thread
#define STAGE(buf, k0) do {                                                     \
    _Pragma("unroll")                                                           \
    for (int b_ = 0; b_ < 4; ++b_) {                                            \
      int doff = off + b_*8192;                                                 \
      int row  = doff >> 7;                                                     \
      int sch  = (((doff >> 4) & 7) ^ (row & 7)) << 4;                          \
      gload16(Ab + ((size_t)(m0+row)*K + (k0))*2 + sch, (char*)lds[buf][0] + doff); \
      gload16(Bb + ((size_t)(n0+row)*K + (k0))*2 + sch, (char*)lds[buf][1] + doff); \
    }                                                                           \
  } while (0)

  const int ntiles = KC >> 6;
  STAGE(0, kbeg);
  STAGE(1, kbeg + 64);
  int cur = 0;

  for (int it = 0; it < ntiles; ++it) {
    if (it + 1 < ntiles) asm volatile("s_waitcnt vmcnt(8)" ::: "memory");
    else                 asm volatile("s_waitcnt vmcnt(0)" ::: "memory");
    __builtin_amdgcn_s_barrier();
    __builtin_amdgcn_sched_barrier(0);

    const char* Ac = (const char*)lds[cur][0];
    const char* Bc = (const char*)lds[cur][1];
    #pragma unroll
    for (int kk = 0; kk < 2; ++kk) {
      const int lob = kk*64 + (kb << 1);
      short8v bfr[4];
      #pragma unroll
      for (int j = 0; j < 4; ++j) {
        const int row = wc*64 + j*16 + l15;
        const char* bp = Bc + row*128;
        bfr[j] = CAT8(*(const short4v*)(bp + SWZ(lob, row)),
                      *(const short4v*)(bp + SWZ(lob + 32, row)));
      }
      __builtin_amdgcn_s_setprio(1);
      #pragma unroll
      for (int i = 0; i < 8; ++i) {
        const int row = wr*128 + i*16 + l15;
        const char* ap = Ac + row*128;
        short8v a = CAT8(*(const short4v*)(ap + SWZ(lob, row)),
                         *(const short4v*)(ap + SWZ(lob + 32, row)));
        #pragma unroll
        for (int j = 0; j < 4; ++j) acc[i][j] = MFMA16(a, bfr[j], acc[i][j]);
      }
      __builtin_amdgcn_s_setprio(0);
    }
    __builtin_amdgcn_sched_barrier(0);
    __builtin_amdgcn_s_barrier();
    if (it + 2 < ntiles) STAGE(cur, kbeg + (it+2)*64);
    cur ^= 1;
  }
#undef STAGE

  #pragma unroll
  for (int i = 0; i < 8; ++i) {
    int row0 = m0 + wr*128 + i*16 + ((lane>>4)<<2);
    #pragma unroll
    for (int j = 0; j < 4; ++j) {
      int col = n0 + wc*64 + j*16 + l15;
      #pragma unroll
      for (int r = 0; r < 4; ++r)
        atomicAdd(&C[(size_t)(row0+r)*ldc + col], acc[i][j][r]);
    }
  }
}

// ---------------- fused RMSNorm + RoPE; V transpose-convert (reads f32 QKV) ----------------
__global__ __launch_bounds__(256) void k_normrope(const float* __restrict__ qkv,
    const float* __restrict__ cosb, const float* __restrict__ sinb,
    const float* __restrict__ qg, const float* __restrict__ kg,
    bf16* __restrict__ Qb, bf16* __restrict__ Kb, bf16* __restrict__ Vt) {
  int wid = blockIdx.x*4 + (threadIdx.x>>6);
  int lane = threadIdx.x & 63;
  int s = wid / 48, r = wid - s*48;
  int col;
  if (r < 32) col = r*64;
  else if (r < 40) col = 2048 + (r-32)*64;
  else col = 2560 + (r-40)*64;
  float v = qkv[(size_t)s*3072 + col + lane];
  if (r < 40) {
    float ss = v*v;
    #pragma unroll
    for (int o = 32; o; o >>= 1) ss += __shfl_xor(ss, o);
    float rms = rsqrtf(ss*(1.0f/64.0f) + 1e-6f);
    float g = (r < 32 ? qg : kg)[lane];
    float tn = v*rms*g;
    float other = __shfl_xor(tn, 32);
    float rot = (lane < 32) ? -other : other;
    float outv = tn*cosb[s*64+lane] + rot*sinb[s*64+lane];
    if (r < 32) Qb[((size_t)r*2048 + s)*64 + lane] = __float2bfloat16(outv);
    else        Kb[((size_t)(r-32)*2048 + s)*64 + lane] = __float2bfloat16(outv);
  } else {
    Vt[(size_t)(r-40)*64*2048 + (size_t)lane*2048 + s] = __float2bfloat16(v);
  }
}

// ---------------- causal flash attention v3: swapped-operand in-register softmax ----
#define SCALE2 0.18033688011f   /* (1/sqrt(64)) * log2(e) */
__global__ __launch_bounds__(512) void k_attn(const bf16* __restrict__ Qb, const bf16* __restrict__ Kb,
                                              const bf16* __restrict__ Vt, bf16* __restrict__ attnb) {
  __shared__ bf16 Ksm[64][68];
  __shared__ bf16 Vsm[64][68];
  const int t = threadIdx.x, lane = t & 63, w = t >> 6;
  const int bid = blockIdx.x;
  const int h = bid & 31;
  const int qi = 15 - (bid >> 5);          // heavy blocks first
  const int qb0 = qi * 128;
  const int kvh = h >> 2;
  const int kb = (lane>>4)*4;
  const int l15 = lane & 15;

  const bf16* Qh = Qb + (size_t)h*2048*64;
  const bf16* Kh = Kb + (size_t)kvh*2048*64;
  const bf16* Vh = Vt + (size_t)kvh*64*2048;

  const int qrow = qb0 + w*16 + l15;       // this lane's q-row (replicated x4 groups)
  short4v qlo[2], qhi[2];
  #pragma unroll
  for (int kk = 0; kk < 2; ++kk) {
    qlo[kk] = *(const short4v*)(Qh + (size_t)qrow*64 + kk*32 + kb);
    qhi[kk] = *(const short4v*)(Qh + (size_t)qrow*64 + kk*32 + 16 + kb);
  }

  float m_ = -3e38f, ls = 0.f;
  f32x4 o2[4];
  #pragma unroll
  for (int j = 0; j < 4; ++j) o2[j] = 0.f;

  const int srow = t >> 3;                 // staging: 512 thr, 1 int4 each for K and V
  const int sc8  = (t & 7) * 8;

  const int nt = 2*qi + 2;
  for (int tt = 0; tt < nt; ++tt) {
    *(int4*)(&Ksm[srow][sc8]) = *(const int4*)(Kh + ((size_t)(tt*64 + srow))*64 + sc8);
    *(int4*)(&Vsm[srow][sc8]) = *(const int4*)(Vh + (size_t)srow*2048 + tt*64 + sc8);
    __syncthreads();

    // S^T = K Q^T -> sAcc[j]: kv-block j, q = l15
    f32x4 sAcc[4];
    #pragma unroll
    for (int j = 0; j < 4; ++j) sAcc[j] = 0.f;
    __builtin_amdgcn_s_setprio(1);
    #pragma unroll
    for (int kk = 0; kk < 2; ++kk) {
      short8v bq = CAT8(qlo[kk], qhi[kk]);
      #pragma unroll
      for (int j = 0; j < 4; ++j) {
        const bf16* kp = &Ksm[j*16 + l15][kk*32 + kb];
        short8v ak = CAT8(*(const short4v*)kp, *(const short4v*)(kp + 16));
        sAcc[j] = MFMA16(ak, bq, sAcc[j]);
      }
    }
    __builtin_amdgcn_s_setprio(0);

    float p[4][4];
    #pragma unroll
    for (int j = 0; j < 4; ++j)
      #pragma unroll
      for (int r = 0; r < 4; ++r) p[j][r] = sAcc[j][r]*SCALE2;
    if (tt*64 + 63 > qb0 + w*16) {
      #pragma unroll
      for (int j = 0; j < 4; ++j) {
        #pragma unroll
        for (int r = 0; r < 4; ++r)
          if (tt*64 + j*16 + kb + r > qrow) p[j][r] = -3e38f;
      }
    }

    float mx = p[0][0];
    #pragma unroll
    for (int j = 0; j < 4; ++j)
      #pragma unroll
      for (int r = 0; r < 4; ++r) mx = fmaxf(mx, p[j][r]);
    mx = fmaxf(mx, __shfl_xor(mx, 16));
    mx = fmaxf(mx, __shfl_xor(mx, 32));
    float mn = fmaxf(m_, mx);
    float alpha = exp2f(m_ - mn);
    m_ = mn;
    ls *= alpha;
    #pragma unroll
    for (int j = 0; j < 4; ++j) o2[j] *= alpha;

    float rs = 0.f;
    #pragma unroll
    for (int j = 0; j < 4; ++j)
      #pragma unroll
      for (int r = 0; r < 4; ++r) {
        float e = exp2f(p[j][r] - mn);
        p[j][r] = e;
        rs += e;
      }
    rs += __shfl_xor(rs, 16);
    rs += __shfl_xor(rs, 32);
    ls += rs;

    short8v pb[2];
    #pragma unroll
    for (int kk = 0; kk < 2; ++kk) {
      short8v v;
      v[0] = f2bs(p[2*kk][0]);   v[1] = f2bs(p[2*kk][1]);
      v[2] = f2bs(p[2*kk][2]);   v[3] = f2bs(p[2*kk][3]);
      v[4] = f2bs(p[2*kk+1][0]); v[5] = f2bs(p[2*kk+1][1]);
      v[6] = f2bs(p[2*kk+1][2]); v[7] = f2bs(p[2*kk+1][3]);
      pb[kk] = v;
    }

    // O^T += V^T P -> o2[j]: d-block j, q = l15
    __builtin_amdgcn_s_setprio(1);
    #pragma unroll
    for (int kk = 0; kk < 2; ++kk) {
      #pragma unroll
      for (int j = 0; j < 4; ++j) {
        const bf16* vp = &Vsm[j*16 + l15][kk*32 + kb];
        short8v av = CAT8(*(const short4v*)vp, *(const short4v*)(vp + 16));
        o2[j] = MFMA16(av, pb[kk], o2[j]);
      }
    }
    __builtin_amdgcn_s_setprio(0);
    __syncthreads();
  }

  float inv = 1.0f / ls;
  #pragma unroll
  for (int j = 0; j < 4; ++j)
    #pragma unroll
    for (int r = 0; r < 4; ++r)
      attnb[(size_t)qrow*2048 + h*64 + j*16 + kb + r] = __float2bfloat16(o2[j][r]*inv);
}

extern "C" void kernel_launch(void* const* d_in, const int* in_sizes, int n_in,
                              void* d_out, int out_size, void* d_ws, size_t ws_size,
                              hipStream_t stream) {
  const float* x    = (const float*)d_in[0];
  const float* cosb = (const float*)d_in[2];
  const float* sinb = (const float*)d_in[3];
  const float* Wq   = (const float*)d_in[4];
  const float* Wk   = (const float*)d_in[5];
  const float* Wv   = (const float*)d_in[6];
  const float* Wo   = (const float*)d_in[7];
  const float* qg   = (const float*)d_in[8];
  const float* kg   = (const float*)d_in[9];
  float* out = (float*)d_out;

  char* ws = (char*)d_ws;
  // phase 1-2 layout
  bf16*  xb    = (bf16*)(ws);                    // 8 MB    [2048][2048]
  bf16*  WqT   = (bf16*)(ws + 8388608);          // 8 MB    [2048][2048]
  bf16*  WkT   = (bf16*)(ws + 16777216);         // 2 MB
  bf16*  WvT   = (bf16*)(ws + 18874368);         // 2 MB
  bf16*  WoT   = (bf16*)(ws + 20971520);         // 8 MB    (live until out-proj)
  float* QKVf  = (float*)(ws + 29360128);        // 25.2 MB [2048][3072] f32 (atomic target)
  // phase 3-4 layout (overlays dead xb/WqT/WkT/WvT)
  bf16*  Qb    = (bf16*)(ws);                    // 8 MB    [32][2048][64]
  bf16*  Kb    = (bf16*)(ws + 8388608);          // 2 MB    [8][2048][64]
  bf16*  Vt    = (bf16*)(ws + 10485760);         // 2 MB    [8][64][2048]
  bf16*  attnb = (bf16*)(ws + 29360128);         // 8 MB    (overlays dead QKVf)

  hipMemsetAsync(QKVf, 0, 25165824, stream);
  hipMemsetAsync(out, 0, (size_t)out_size*4, stream);

  k_cvt_x<<<4096, 256, 0, stream>>>(x, xb);
  k_transpose_cvt<<<dim3(32, 32), 256, 0, stream>>>(Wq, WqT, 2048, 2048);
  k_transpose_cvt<<<dim3(8, 32),  256, 0, stream>>>(Wk, WkT, 2048, 512);
  k_transpose_cvt<<<dim3(8, 32),  256, 0, stream>>>(Wv, WvT, 2048, 512);
  k_transpose_cvt<<<dim3(32, 32), 256, 0, stream>>>(Wo, WoT, 2048, 2048);

  // QKV projection: 256x256 tiles, split-K x2 -> 192 blocks (%8==0)
  k_gemm256<<<dim3(12, 8, 2), 512, 0, stream>>>(xb, WqT, QKVf, 2048, 3072, 2048, 1024, 3072);
  k_normrope<<<24576, 256, 0, stream>>>(QKVf, cosb, sinb, qg, kg, Qb, Kb, Vt);
  k_attn<<<512, 512, 0, stream>>>(Qb, Kb, Vt, attnb);
  // output projection: 256x256 tiles, split-K x4 -> 256 blocks (%8==0)
  k_gemm256<<<dim3(8, 8, 4), 512, 0, stream>>>(attnb, WoT, out, 2048, 2048, 2048, 512, 2048);
}